// Round 3
// baseline (313.233 us; speedup 1.0000x reference)
//
#include <hip/hip_runtime.h>
#include <hip/hip_bf16.h>

#define NROWS 400000
#define MSEL  100000
#define FDIM  128
#define D0 256
#define D1 256
#define D2 128

typedef __attribute__((ext_vector_type(8))) short short8;
typedef __attribute__((ext_vector_type(4))) float f32x4;
typedef __attribute__((ext_vector_type(4))) unsigned short ushort4v;

__device__ __forceinline__ unsigned short f2bf(float f) {
    unsigned int u = __float_as_uint(f);
    unsigned int r = (u + 0x7fffu + ((u >> 16) & 1u)) >> 16;
    return (unsigned short)r;
}

__device__ __forceinline__ float elu(float v) {
    return v > 0.f ? v : (__expf(v) - 1.f);
}

// ---------------------------------------------------------------------------
// Repack f32 weights into bf16 B-fragment order for mfma_f32_16x16x32_bf16.
// Tile (kt,nt) is 32x16; lane l holds B[kt*32+(l>>4)*8+j][nt*16+(l&15)], 8 bf16
// contiguous per lane (one dwordx4).  ws: W0p [0,32768) shorts,
// W1p [32768,98304), W2p [98304,131072).
// ---------------------------------------------------------------------------
__global__ void pack_weights(const float* __restrict__ W0,
                             const float* __restrict__ W1,
                             const float* __restrict__ W2,
                             short* __restrict__ out) {
    int e = blockIdx.x * 256 + threadIdx.x;
    if (e >= 131072) return;
    const float* W; int N; int base; int le;
    if (e < 32768)       { W = W0; N = 256; base = 0;     le = e; }
    else if (e < 98304)  { W = W1; N = 256; base = 32768; le = e - 32768; }
    else                 { W = W2; N = 128; base = 98304; le = e - 98304; }
    int t    = le >> 9;
    int r    = le & 511;
    int lane = r >> 3;
    int j    = r & 7;
    int ntiles = N >> 4;
    int kt = t / ntiles, nt = t % ntiles;
    int k = kt * 32 + (lane >> 4) * 8 + j;
    int n = nt * 16 + (lane & 15);
    out[base + le] = (short)f2bf(W[k * N + n]);
}

__global__ void copy_x(const float4* __restrict__ x, float4* __restrict__ out, int n4) {
    int i = blockIdx.x * blockDim.x + threadIdx.x;
    int stride = gridDim.x * blockDim.x;
    for (; i < n4; i += stride) out[i] = x[i];
}

// ---------------------------------------------------------------------------
// Gather -> 3-layer ELU MLP (bf16 MFMA).  Block = 256 thr = 4 waves, 32 rows.
// Each wave computes ALL 32 rows x a 64-col slice (32-col for layer 2);
// B-fragments register-resident per layer.  LDS 40KB -> 4 blocks/CU.
//   xreg [0,4096) shorts : gathered x (32 x 128 bf16)
//   h0   [4096,12288)    : 32 x 256
//   h1   [12288,20480)   : 32 x 256
// XOR swizzle shortIdx ^= (row&7)<<3 breaks ds_read_b128 bank conflicts.
// SPLIT: write up (bf16) to ws; else fused atomicAdd.
// ---------------------------------------------------------------------------
template <bool SPLIT>
__global__ __launch_bounds__(256) void mlp_compute(
    const float* __restrict__ x, const int* __restrict__ sel,
    const short* __restrict__ wp,
    const float* __restrict__ b0v, const float* __restrict__ b1v,
    const float* __restrict__ b2v,
    unsigned short* __restrict__ upOut, float* __restrict__ out) {
    __shared__ __align__(16) short lds[20480];

    const int tid  = threadIdx.x;
    const int lane = tid & 63;
    const int w    = tid >> 6;
    const int rowBase = blockIdx.x * 32;
    const int lm = lane & 15;
    const int kq = lane >> 4;
    const int sxz = (lm & 7) << 3;

    const short* W0p = wp;
    const short* W1p = wp + 32768;
    const short* W2p = wp + 98304;

    // prefetch layer-0 B fragments (hide under gather)
    short8 B0[4][4];
    #pragma unroll
    for (int kt = 0; kt < 4; kt++)
        #pragma unroll
        for (int ntl = 0; ntl < 4; ntl++)
            B0[kt][ntl] = *(const short8*)(W0p + ((kt * 16 + (w * 4 + ntl)) * 512 + lane * 8));

    // gather: 32 rows x 128 f32 -> bf16 into xreg
    const float4* xv = (const float4*)x;
    #pragma unroll
    for (int it = 0; it < 4; it++) {
        int i = it * 256 + tid;
        int row = i >> 5, seg = i & 31;
        float4 v = xv[(size_t)sel[rowBase + row] * 32 + seg];
        ushort4v p = { f2bf(v.x), f2bf(v.y), f2bf(v.z), f2bf(v.w) };
        *(ushort4v*)(&lds[(row * 128 + seg * 4) ^ ((row & 7) << 3)]) = p;
    }
    __syncthreads();

    const f32x4 zero4 = {0.f, 0.f, 0.f, 0.f};

    // ===== layer 0: (32x128) @ W0(128x256) =====
    {
        f32x4 acc[2][4];
        #pragma unroll
        for (int i = 0; i < 2; i++)
            #pragma unroll
            for (int j = 0; j < 4; j++) acc[i][j] = zero4;
        #pragma unroll
        for (int rt = 0; rt < 2; rt++) {
            short8 a[4];
            int rowA = rt * 16 + lm;
            #pragma unroll
            for (int kt = 0; kt < 4; kt++)
                a[kt] = *(const short8*)(&lds[(rowA * 128 + kt * 32 + kq * 8) ^ sxz]);
            #pragma unroll
            for (int ntl = 0; ntl < 4; ntl++)
                #pragma unroll
                for (int kt = 0; kt < 4; kt++)
                    acc[rt][ntl] = __builtin_amdgcn_mfma_f32_16x16x32_bf16(a[kt], B0[kt][ntl], acc[rt][ntl], 0, 0, 0);
        }
        #pragma unroll
        for (int ntl = 0; ntl < 4; ntl++) {
            int col = (w * 4 + ntl) * 16 + lm;
            float bias = b0v[col];
            #pragma unroll
            for (int rt = 0; rt < 2; rt++)
                #pragma unroll
                for (int r = 0; r < 4; r++) {
                    int row = rt * 16 + kq * 4 + r;
                    float v = elu(acc[rt][ntl][r] + bias);
                    lds[4096 + ((row * 256 + col) ^ ((row & 7) << 3))] = (short)f2bf(v);
                }
        }
    }
    __syncthreads();

    // ===== layer 1: (32x256) @ W1(256x256), 2 col-passes =====
    #pragma unroll
    for (int pass = 0; pass < 2; pass++) {
        short8 B1[8][2];
        #pragma unroll
        for (int kt = 0; kt < 8; kt++)
            #pragma unroll
            for (int p = 0; p < 2; p++)
                B1[kt][p] = *(const short8*)(W1p + ((kt * 16 + (w * 4 + pass * 2 + p)) * 512 + lane * 8));
        f32x4 acc[2][2];
        #pragma unroll
        for (int i = 0; i < 2; i++)
            #pragma unroll
            for (int j = 0; j < 2; j++) acc[i][j] = zero4;
        #pragma unroll
        for (int rt = 0; rt < 2; rt++) {
            short8 a[8];
            int rowA = rt * 16 + lm;
            #pragma unroll
            for (int kt = 0; kt < 8; kt++)
                a[kt] = *(const short8*)(&lds[4096 + ((rowA * 256 + kt * 32 + kq * 8) ^ sxz)]);
            #pragma unroll
            for (int p = 0; p < 2; p++)
                #pragma unroll
                for (int kt = 0; kt < 8; kt++)
                    acc[rt][p] = __builtin_amdgcn_mfma_f32_16x16x32_bf16(a[kt], B1[kt][p], acc[rt][p], 0, 0, 0);
        }
        #pragma unroll
        for (int p = 0; p < 2; p++) {
            int col = (w * 4 + pass * 2 + p) * 16 + lm;
            float bias = b1v[col];
            #pragma unroll
            for (int rt = 0; rt < 2; rt++)
                #pragma unroll
                for (int r = 0; r < 4; r++) {
                    int row = rt * 16 + kq * 4 + r;
                    float v = elu(acc[rt][p][r] + bias);
                    lds[12288 + ((row * 256 + col) ^ ((row & 7) << 3))] = (short)f2bf(v);
                }
        }
    }
    __syncthreads();

    // ===== layer 2: (32x256) @ W2(256x128) =====
    {
        short8 B2[8][2];
        #pragma unroll
        for (int kt = 0; kt < 8; kt++)
            #pragma unroll
            for (int ntl = 0; ntl < 2; ntl++)
                B2[kt][ntl] = *(const short8*)(W2p + ((kt * 8 + (w * 2 + ntl)) * 512 + lane * 8));

        f32x4 acc[2][2];
        #pragma unroll
        for (int i = 0; i < 2; i++)
            #pragma unroll
            for (int j = 0; j < 2; j++) acc[i][j] = zero4;
        #pragma unroll
        for (int rt = 0; rt < 2; rt++) {
            short8 a[8];
            int rowA = rt * 16 + lm;
            #pragma unroll
            for (int kt = 0; kt < 8; kt++)
                a[kt] = *(const short8*)(&lds[12288 + ((rowA * 256 + kt * 32 + kq * 8) ^ sxz)]);
            #pragma unroll
            for (int ntl = 0; ntl < 2; ntl++)
                #pragma unroll
                for (int kt = 0; kt < 8; kt++)
                    acc[rt][ntl] = __builtin_amdgcn_mfma_f32_16x16x32_bf16(a[kt], B2[kt][ntl], acc[rt][ntl], 0, 0, 0);
        }
        #pragma unroll
        for (int ntl = 0; ntl < 2; ntl++) {
            int col = (w * 2 + ntl) * 16 + lm;
            float bias = b2v[col];
            #pragma unroll
            for (int rt = 0; rt < 2; rt++)
                #pragma unroll
                for (int r = 0; r < 4; r++) {
                    int row = rt * 16 + kq * 4 + r;
                    int grow = rowBase + row;
                    float v = elu(acc[rt][ntl][r] + bias);
                    if (SPLIT) {
                        upOut[(size_t)grow * 128 + col] = f2bf(v);
                    } else {
                        atomicAdd(out + (size_t)sel[grow] * 128 + col, v);
                    }
                }
        }
    }
}

// ---------------------------------------------------------------------------
// Scatter: out[sel[j]][:] += up[j][:]  (atomic, grid-strided, 4 cols/thread)
// ---------------------------------------------------------------------------
__global__ void scatter_add(const unsigned short* __restrict__ up,
                            const int* __restrict__ sel,
                            float* __restrict__ out) {
    const int total = MSEL * 32;               // 4-col chunks
    int g = blockIdx.x * 256 + threadIdx.x;
    int stride = gridDim.x * 256;
    for (; g < total; g += stride) {
        int j = g >> 5;
        int q = (g & 31) * 4;
        int r = sel[j];
        ushort4v u = *(const ushort4v*)(up + (size_t)j * 128 + q);
        float* p = out + (size_t)r * 128 + q;
        #pragma unroll
        for (int c = 0; c < 4; c++) {
            float f = __uint_as_float(((unsigned int)u[c]) << 16);
            atomicAdd(p + c, f);
        }
    }
}

extern "C" void kernel_launch(void* const* d_in, const int* in_sizes, int n_in,
                              void* d_out, int out_size, void* d_ws, size_t ws_size,
                              hipStream_t stream) {
    const float* x   = (const float*)d_in[0];
    const int*   sel = (const int*)d_in[1];
    const float* W0  = (const float*)d_in[2];
    const float* b0  = (const float*)d_in[3];
    const float* W1  = (const float*)d_in[4];
    const float* b1  = (const float*)d_in[5];
    const float* W2  = (const float*)d_in[6];
    const float* b2  = (const float*)d_in[7];
    float* out = (float*)d_out;
    short* wp  = (short*)d_ws;                               // 262144 B
    unsigned short* up = (unsigned short*)((char*)d_ws + 262144);  // 25.6 MB

    const size_t need = 262144 + (size_t)MSEL * 128 * 2;

    pack_weights<<<512, 256, 0, stream>>>(W0, W1, W2, wp);
    copy_x<<<4096, 256, 0, stream>>>((const float4*)x, (float4*)out, NROWS * FDIM / 4);
    if (ws_size >= need) {
        mlp_compute<true><<<MSEL / 32, 256, 0, stream>>>(x, sel, wp, b0, b1, b2, up, out);
        scatter_add<<<2048, 256, 0, stream>>>(up, sel, out);
    } else {
        mlp_compute<false><<<MSEL / 32, 256, 0, stream>>>(x, sel, wp, b0, b1, b2, up, out);
    }
}

// Round 4
// 154.247 us; speedup vs baseline: 2.0307x; 2.0307x over previous
//
#include <hip/hip_runtime.h>
#include <hip/hip_bf16.h>

#define NROWS 400000
#define MSEL  100000
#define FDIM  128
#define D0 256
#define D1 256
#define D2 128

typedef __attribute__((ext_vector_type(8))) short short8;
typedef __attribute__((ext_vector_type(4))) float f32x4;
typedef __attribute__((ext_vector_type(4))) unsigned short ushort4v;

__device__ __forceinline__ unsigned short f2bf(float f) {
    unsigned int u = __float_as_uint(f);
    unsigned int r = (u + 0x7fffu + ((u >> 16) & 1u)) >> 16;
    return (unsigned short)r;
}

__device__ __forceinline__ float elu(float v) {
    return v > 0.f ? v : (__expf(v) - 1.f);
}

// ---------------------------------------------------------------------------
// Repack f32 weights into bf16 B-fragment order for mfma_f32_16x16x32_bf16.
// Tile (kt,nt) is 32x16; lane l holds B[kt*32+(l>>4)*8+j][nt*16+(l&15)], 8 bf16
// contiguous per lane (one dwordx4).  ws: W0p [0,32768) shorts,
// W1p [32768,98304), W2p [98304,131072).
// ---------------------------------------------------------------------------
__global__ void pack_weights(const float* __restrict__ W0,
                             const float* __restrict__ W1,
                             const float* __restrict__ W2,
                             short* __restrict__ out) {
    int e = blockIdx.x * 256 + threadIdx.x;
    if (e >= 131072) return;
    const float* W; int N; int base; int le;
    if (e < 32768)       { W = W0; N = 256; base = 0;     le = e; }
    else if (e < 98304)  { W = W1; N = 256; base = 32768; le = e - 32768; }
    else                 { W = W2; N = 128; base = 98304; le = e - 98304; }
    int t    = le >> 9;
    int r    = le & 511;
    int lane = r >> 3;
    int j    = r & 7;
    int ntiles = N >> 4;
    int kt = t / ntiles, nt = t % ntiles;
    int k = kt * 32 + (lane >> 4) * 8 + j;
    int n = nt * 16 + (lane & 15);
    out[base + le] = (short)f2bf(W[k * N + n]);
}

__global__ void copy_x(const float4* __restrict__ x, float4* __restrict__ out, int n4) {
    int i = blockIdx.x * blockDim.x + threadIdx.x;
    int stride = gridDim.x * blockDim.x;
    for (; i < n4; i += stride) out[i] = x[i];
}

// ---------------------------------------------------------------------------
// Inverted index of sel: head[r] -> last j with sel[j]==r, next[j] -> chain.
// ---------------------------------------------------------------------------
__global__ void init_head(int* __restrict__ head) {
    int i = blockIdx.x * 256 + threadIdx.x;
    int s = gridDim.x * 256;
    for (; i < NROWS; i += s) head[i] = -1;
}

__global__ void build_links(const int* __restrict__ sel,
                            int* __restrict__ head, int* __restrict__ next) {
    int j = blockIdx.x * 256 + threadIdx.x;
    if (j < MSEL) {
        int r = sel[j];
        next[j] = atomicExch(head + r, j);
    }
}

// ---------------------------------------------------------------------------
// Gather -> 3-layer ELU MLP (bf16 MFMA).  Block = 256 thr = 4 waves, 32 rows.
// Each wave computes ALL 32 rows x a 64-col slice (32-col for layer 2);
// B-fragments register-resident per layer.  LDS 40KB -> 4 blocks/CU.
// XOR swizzle shortIdx ^= (row&7)<<3 breaks ds_read_b128 bank conflicts.
// SPLIT: write up (bf16) to ws; else fused atomicAdd.
// ---------------------------------------------------------------------------
template <bool SPLIT>
__global__ __launch_bounds__(256) void mlp_compute(
    const float* __restrict__ x, const int* __restrict__ sel,
    const short* __restrict__ wp,
    const float* __restrict__ b0v, const float* __restrict__ b1v,
    const float* __restrict__ b2v,
    unsigned short* __restrict__ upOut, float* __restrict__ out) {
    __shared__ __align__(16) short lds[20480];

    const int tid  = threadIdx.x;
    const int lane = tid & 63;
    const int w    = tid >> 6;
    const int rowBase = blockIdx.x * 32;
    const int lm = lane & 15;
    const int kq = lane >> 4;
    const int sxz = (lm & 7) << 3;

    const short* W0p = wp;
    const short* W1p = wp + 32768;
    const short* W2p = wp + 98304;

    // prefetch layer-0 B fragments (hide under gather)
    short8 B0[4][4];
    #pragma unroll
    for (int kt = 0; kt < 4; kt++)
        #pragma unroll
        for (int ntl = 0; ntl < 4; ntl++)
            B0[kt][ntl] = *(const short8*)(W0p + ((kt * 16 + (w * 4 + ntl)) * 512 + lane * 8));

    // gather: 32 rows x 128 f32 -> bf16 into LDS
    const float4* xv = (const float4*)x;
    #pragma unroll
    for (int it = 0; it < 4; it++) {
        int i = it * 256 + tid;
        int row = i >> 5, seg = i & 31;
        float4 v = xv[(size_t)sel[rowBase + row] * 32 + seg];
        ushort4v p = { f2bf(v.x), f2bf(v.y), f2bf(v.z), f2bf(v.w) };
        *(ushort4v*)(&lds[(row * 128 + seg * 4) ^ ((row & 7) << 3)]) = p;
    }
    __syncthreads();

    const f32x4 zero4 = {0.f, 0.f, 0.f, 0.f};

    // ===== layer 0: (32x128) @ W0(128x256) =====
    {
        f32x4 acc[2][4];
        #pragma unroll
        for (int i = 0; i < 2; i++)
            #pragma unroll
            for (int j = 0; j < 4; j++) acc[i][j] = zero4;
        #pragma unroll
        for (int rt = 0; rt < 2; rt++) {
            short8 a[4];
            int rowA = rt * 16 + lm;
            #pragma unroll
            for (int kt = 0; kt < 4; kt++)
                a[kt] = *(const short8*)(&lds[(rowA * 128 + kt * 32 + kq * 8) ^ sxz]);
            #pragma unroll
            for (int ntl = 0; ntl < 4; ntl++)
                #pragma unroll
                for (int kt = 0; kt < 4; kt++)
                    acc[rt][ntl] = __builtin_amdgcn_mfma_f32_16x16x32_bf16(a[kt], B0[kt][ntl], acc[rt][ntl], 0, 0, 0);
        }
        #pragma unroll
        for (int ntl = 0; ntl < 4; ntl++) {
            int col = (w * 4 + ntl) * 16 + lm;
            float bias = b0v[col];
            #pragma unroll
            for (int rt = 0; rt < 2; rt++)
                #pragma unroll
                for (int r = 0; r < 4; r++) {
                    int row = rt * 16 + kq * 4 + r;
                    float v = elu(acc[rt][ntl][r] + bias);
                    lds[4096 + ((row * 256 + col) ^ ((row & 7) << 3))] = (short)f2bf(v);
                }
        }
    }
    __syncthreads();

    // ===== layer 1: (32x256) @ W1(256x256), 2 col-passes =====
    #pragma unroll
    for (int pass = 0; pass < 2; pass++) {
        short8 B1[8][2];
        #pragma unroll
        for (int kt = 0; kt < 8; kt++)
            #pragma unroll
            for (int p = 0; p < 2; p++)
                B1[kt][p] = *(const short8*)(W1p + ((kt * 16 + (w * 4 + pass * 2 + p)) * 512 + lane * 8));
        f32x4 acc[2][2];
        #pragma unroll
        for (int i = 0; i < 2; i++)
            #pragma unroll
            for (int j = 0; j < 2; j++) acc[i][j] = zero4;
        #pragma unroll
        for (int rt = 0; rt < 2; rt++) {
            short8 a[8];
            int rowA = rt * 16 + lm;
            #pragma unroll
            for (int kt = 0; kt < 8; kt++)
                a[kt] = *(const short8*)(&lds[4096 + ((rowA * 256 + kt * 32 + kq * 8) ^ sxz)]);
            #pragma unroll
            for (int p = 0; p < 2; p++)
                #pragma unroll
                for (int kt = 0; kt < 8; kt++)
                    acc[rt][p] = __builtin_amdgcn_mfma_f32_16x16x32_bf16(a[kt], B1[kt][p], acc[rt][p], 0, 0, 0);
        }
        #pragma unroll
        for (int p = 0; p < 2; p++) {
            int col = (w * 4 + pass * 2 + p) * 16 + lm;
            float bias = b1v[col];
            #pragma unroll
            for (int rt = 0; rt < 2; rt++)
                #pragma unroll
                for (int r = 0; r < 4; r++) {
                    int row = rt * 16 + kq * 4 + r;
                    float v = elu(acc[rt][p][r] + bias);
                    lds[12288 + ((row * 256 + col) ^ ((row & 7) << 3))] = (short)f2bf(v);
                }
        }
    }
    __syncthreads();

    // ===== layer 2: (32x256) @ W2(256x128) =====
    {
        short8 B2[8][2];
        #pragma unroll
        for (int kt = 0; kt < 8; kt++)
            #pragma unroll
            for (int ntl = 0; ntl < 2; ntl++)
                B2[kt][ntl] = *(const short8*)(W2p + ((kt * 8 + (w * 2 + ntl)) * 512 + lane * 8));

        f32x4 acc[2][2];
        #pragma unroll
        for (int i = 0; i < 2; i++)
            #pragma unroll
            for (int j = 0; j < 2; j++) acc[i][j] = zero4;
        #pragma unroll
        for (int rt = 0; rt < 2; rt++) {
            short8 a[8];
            int rowA = rt * 16 + lm;
            #pragma unroll
            for (int kt = 0; kt < 8; kt++)
                a[kt] = *(const short8*)(&lds[12288 + ((rowA * 256 + kt * 32 + kq * 8) ^ sxz)]);
            #pragma unroll
            for (int ntl = 0; ntl < 2; ntl++)
                #pragma unroll
                for (int kt = 0; kt < 8; kt++)
                    acc[rt][ntl] = __builtin_amdgcn_mfma_f32_16x16x32_bf16(a[kt], B2[kt][ntl], acc[rt][ntl], 0, 0, 0);
        }
        #pragma unroll
        for (int ntl = 0; ntl < 2; ntl++) {
            int col = (w * 2 + ntl) * 16 + lm;
            float bias = b2v[col];
            #pragma unroll
            for (int rt = 0; rt < 2; rt++)
                #pragma unroll
                for (int r = 0; r < 4; r++) {
                    int row = rt * 16 + kq * 4 + r;
                    int grow = rowBase + row;
                    float v = elu(acc[rt][ntl][r] + bias);
                    if (SPLIT) {
                        upOut[(size_t)grow * 128 + col] = f2bf(v);
                    } else {
                        atomicAdd(out + (size_t)sel[grow] * 128 + col, v);
                    }
                }
        }
    }
}

// ---------------------------------------------------------------------------
// merge: out[r] = x[r] + sum_{j in chain(r)} up[j].  Wave per row, no atomics.
// Chain walk is wave-uniform (all lanes read the same head/next values).
// ---------------------------------------------------------------------------
__global__ __launch_bounds__(256) void merge_out(
    const float2* __restrict__ x2, const unsigned int* __restrict__ up32,
    const int* __restrict__ head, const int* __restrict__ next,
    float2* __restrict__ out2) {
    int wid  = blockIdx.x * 4 + (threadIdx.x >> 6);
    int lane = threadIdx.x & 63;
    int wstride = gridDim.x * 4;
    for (int row = wid; row < NROWS; row += wstride) {
        float2 v = x2[(size_t)row * 64 + lane];
        int j = head[row];
        while (j >= 0) {
            unsigned int u = up32[j * 64 + lane];
            v.x += __uint_as_float(u << 16);
            v.y += __uint_as_float(u & 0xffff0000u);
            j = next[j];
        }
        out2[(size_t)row * 64 + lane] = v;
    }
}

extern "C" void kernel_launch(void* const* d_in, const int* in_sizes, int n_in,
                              void* d_out, int out_size, void* d_ws, size_t ws_size,
                              hipStream_t stream) {
    const float* x   = (const float*)d_in[0];
    const int*   sel = (const int*)d_in[1];
    const float* W0  = (const float*)d_in[2];
    const float* b0  = (const float*)d_in[3];
    const float* W1  = (const float*)d_in[4];
    const float* b1  = (const float*)d_in[5];
    const float* W2  = (const float*)d_in[6];
    const float* b2  = (const float*)d_in[7];
    float* out = (float*)d_out;

    char* wsb = (char*)d_ws;
    short* wp          = (short*)wsb;                                  // 262144 B
    unsigned short* up = (unsigned short*)(wsb + 262144);              // 25.6 MB
    int* head          = (int*)(wsb + 262144 + (size_t)MSEL * 256);    // 1.6 MB
    int* nxt           = head + NROWS;                                 // 0.4 MB
    const size_t need  = 262144 + (size_t)MSEL * 256 + (size_t)NROWS * 4 + (size_t)MSEL * 4;

    pack_weights<<<512, 256, 0, stream>>>(W0, W1, W2, wp);
    if (ws_size >= need) {
        init_head<<<1024, 256, 0, stream>>>(head);
        build_links<<<(MSEL + 255) / 256, 256, 0, stream>>>(sel, head, nxt);
        mlp_compute<true><<<MSEL / 32, 256, 0, stream>>>(x, sel, wp, b0, b1, b2, up, out);
        merge_out<<<4096, 256, 0, stream>>>((const float2*)x, (const unsigned int*)up,
                                            head, nxt, (float2*)out);
    } else {
        copy_x<<<4096, 256, 0, stream>>>((const float4*)x, (float4*)out, NROWS * FDIM / 4);
        mlp_compute<false><<<MSEL / 32, 256, 0, stream>>>(x, sel, wp, b0, b1, b2, up, out);
    }
}